// Round 1
// baseline (82.227 us; speedup 1.0000x reference)
//
#include <hip/hip_runtime.h>
#include <math.h>

// Dims
#define D 2048
#define NH 8
#define NKV 2
#define HD 256
#define DFF 8192
#define W 512
#define PLD 256
#define EPS 1e-6f

__device__ __forceinline__ float warp_sum(float v) {
    #pragma unroll
    for (int off = 32; off > 0; off >>= 1) v += __shfl_down(v, off, 64);
    return v;
}
__device__ __forceinline__ float warp_max(float v) {
    #pragma unroll
    for (int off = 32; off > 0; off >>= 1) v = fmaxf(v, __shfl_down(v, off, 64));
    return v;
}

// block of 256 threads = 4 waves
__device__ __forceinline__ float block_sum256(float v, float* s4) {
    int lane = threadIdx.x & 63, wid = threadIdx.x >> 6;
    v = warp_sum(v);
    if (lane == 0) s4[wid] = v;
    __syncthreads();
    float r = s4[0] + s4[1] + s4[2] + s4[3];
    __syncthreads();
    return r;
}
__device__ __forceinline__ float block_max256(float v, float* s4) {
    int lane = threadIdx.x & 63, wid = threadIdx.x >> 6;
    v = warp_max(v);
    if (lane == 0) s4[wid] = v;
    __syncthreads();
    float r = fmaxf(fmaxf(s4[0], s4[1]), fmaxf(s4[2], s4[3]));
    __syncthreads();
    return r;
}

__device__ __forceinline__ float gelu_tanh(float x) {
    const float c = 0.7978845608028654f; // sqrt(2/pi)
    float t = tanhf(c * (x + 0.044715f * x * x * x));
    return 0.5f * x * (1.0f + t);
}

// ---------- h = rmsnorm(x, w) over D, 1 block x 256 ----------
__global__ void rms_in_kernel(const float* __restrict__ x, const float* __restrict__ w,
                              float* __restrict__ out) {
    __shared__ float s4[4];
    int t = threadIdx.x;
    float v[8], ss = 0.f;
    #pragma unroll
    for (int i = 0; i < 8; i++) { v[i] = x[t + i * 256]; ss += v[i] * v[i]; }
    float tot = block_sum256(ss, s4);
    float rs = rsqrtf(tot / (float)D + EPS);
    #pragma unroll
    for (int i = 0; i < 8; i++) out[t + i * 256] = v[i] * rs * (1.f + w[t + i * 256]);
}

// ---------- fused q/k/v projection: 3072 rows x 2048 cols ----------
__global__ void gemv_qkv(const float* __restrict__ Wq, const float* __restrict__ Wk,
                         const float* __restrict__ Wv, const float* __restrict__ h,
                         float* __restrict__ qraw, float* __restrict__ kraw,
                         float* __restrict__ vraw) {
    int lane = threadIdx.x & 63, wid = threadIdx.x >> 6;
    int row = blockIdx.x * 4 + wid; // 0..3071
    const float* wr;
    float* out;
    if (row < 2048)      { wr = Wq + (size_t)row * D;          out = qraw + row; }
    else if (row < 2560) { wr = Wk + (size_t)(row - 2048) * D; out = kraw + (row - 2048); }
    else                 { wr = Wv + (size_t)(row - 2560) * D; out = vraw + (row - 2560); }
    float acc = 0.f;
    #pragma unroll 4
    for (int it = 0; it < D / 256; it++) {
        int c = it * 256 + lane * 4;
        float4 wv = *reinterpret_cast<const float4*>(wr + c);
        float4 hv = *reinterpret_cast<const float4*>(h + c);
        acc = fmaf(wv.x, hv.x, fmaf(wv.y, hv.y, fmaf(wv.z, hv.z, fmaf(wv.w, hv.w, acc))));
    }
    acc = warp_sum(acc);
    if (lane == 0) *out = acc;
}

// ---------- per-head rmsnorm + RoPE (q,k) / weightless rmsnorm (v) ----------
// grid 12: 0..7 q heads, 8..9 k heads, 10..11 v heads. block 256.
__global__ void head_norm_rope(const float* __restrict__ qraw, const float* __restrict__ kraw,
                               const float* __restrict__ vraw, const float* __restrict__ qw,
                               const float* __restrict__ kw, const float* __restrict__ cosv,
                               const float* __restrict__ sinv, float* __restrict__ qf,
                               float* __restrict__ kf, float* __restrict__ vf) {
    __shared__ float s4[4];
    __shared__ float sn[HD];
    int b = blockIdx.x, t = threadIdx.x;
    const float* in; float* out; const float* w; bool rope;
    if (b < 8)       { in = qraw + b * HD;        out = qf + b * HD;        w = qw;      rope = true;  }
    else if (b < 10) { in = kraw + (b - 8) * HD;  out = kf + (b - 8) * HD;  w = kw;      rope = true;  }
    else             { in = vraw + (b - 10) * HD; out = vf + (b - 10) * HD; w = nullptr; rope = false; }
    float x = in[t];
    float tot = block_sum256(x * x, s4);
    float rs = rsqrtf(tot / (float)HD + EPS);
    float nv = x * rs * (w ? (1.f + w[t]) : 1.f);
    sn[t] = nv;
    __syncthreads();
    float o = nv;
    if (rope) {
        float rh = (t < HD / 2) ? -sn[t + HD / 2] : sn[t - HD / 2];
        o = nv * cosv[t] + rh * sinv[t];
    }
    out[t] = o;
}

// ---------- attention scores: grid 64 = head*8 + wchunk, block 256 (4 waves x 16 w) ----------
__global__ void attn_scores(const float* __restrict__ kvc, const float* __restrict__ kf,
                            const float* __restrict__ mask, const float* __restrict__ qf,
                            const int* __restrict__ ring_p, float* __restrict__ scores) {
    int head = blockIdx.x >> 3, wc = blockIdx.x & 7;
    int kvh = head >> 2; // n_rep = 4
    int lane = threadIdx.x & 63, wid = threadIdx.x >> 6;
    int ring = *ring_p;
    float4 qv = *reinterpret_cast<const float4*>(qf + head * HD + lane * 4);
    const float* Kbase = kvc + (size_t)kvh * W * HD;
    #pragma unroll 4
    for (int i = 0; i < 16; i++) {
        int w = wc * 64 + wid * 16 + i;
        const float* krow = (w == ring) ? (kf + kvh * HD) : (Kbase + (size_t)w * HD);
        float4 kv4 = *reinterpret_cast<const float4*>(krow + lane * 4);
        float acc = qv.x * kv4.x + qv.y * kv4.y + qv.z * kv4.z + qv.w * kv4.w;
        acc = warp_sum(acc);
        if (lane == 0) scores[head * W + w] = acc + mask[w];
    }
}

// ---------- softmax per head (8 blocks x 256) + zero attn_o ----------
__global__ void attn_softmax(float* __restrict__ scores, float* __restrict__ attn_o) {
    __shared__ float s4[4];
    int head = blockIdx.x, t = threadIdx.x;
    float s0 = scores[head * W + t], s1 = scores[head * W + 256 + t];
    float m = block_max256(fmaxf(s0, s1), s4);
    float e0 = expf(s0 - m), e1 = expf(s1 - m);
    float sum = block_sum256(e0 + e1, s4);
    float inv = 1.f / sum;
    scores[head * W + t] = e0 * inv;
    scores[head * W + 256 + t] = e1 * inv;
    attn_o[head * HD + t] = 0.f;
}

// ---------- o partials: grid 64 = head*8 + wchunk, block 256 (thread = d) ----------
__global__ void attn_o_partial(const float* __restrict__ kvc, const float* __restrict__ vf,
                               const float* __restrict__ p, const int* __restrict__ ring_p,
                               float* __restrict__ attn_o) {
    int head = blockIdx.x >> 3, wc = blockIdx.x & 7;
    int kvh = head >> 2;
    int d = threadIdx.x;
    int ring = *ring_p;
    const float* Vbase = kvc + (size_t)(NKV + kvh) * W * HD;
    float acc = 0.f;
    #pragma unroll 4
    for (int i = 0; i < 64; i++) {
        int w = wc * 64 + i;
        float pw = p[head * W + w];
        const float* vrow = (w == ring) ? (vf + kvh * HD) : (Vbase + (size_t)w * HD);
        acc = fmaf(pw, vrow[d], acc);
    }
    atomicAdd(&attn_o[head * HD + d], acc);
}

// ---------- generic GEMV: y[row] = W[row,:] . x, wave-per-row ----------
template <int NC>
__global__ void gemv(const float* __restrict__ Wm, const float* __restrict__ x,
                     float* __restrict__ y) {
    int lane = threadIdx.x & 63, wid = threadIdx.x >> 6;
    int row = blockIdx.x * 4 + wid;
    const float* wr = Wm + (size_t)row * NC;
    float acc = 0.f;
    #pragma unroll 4
    for (int it = 0; it < NC / 256; it++) {
        int c = it * 256 + lane * 4;
        float4 wv = *reinterpret_cast<const float4*>(wr + c);
        float4 xv = *reinterpret_cast<const float4*>(x + c);
        acc = fmaf(wv.x, xv.x, fmaf(wv.y, xv.y, fmaf(wv.z, xv.z, fmaf(wv.w, xv.w, acc))));
    }
    acc = warp_sum(acc);
    if (lane == 0) y[row] = acc;
}

// ---------- fused gate/up GEMV: act[row] = gelu(Wg[row].hn) * (Wu[row].hn) ----------
__global__ void gemv_gateup(const float* __restrict__ Wg, const float* __restrict__ Wu,
                            const float* __restrict__ hn, float* __restrict__ act) {
    int lane = threadIdx.x & 63, wid = threadIdx.x >> 6;
    int row = blockIdx.x * 4 + wid; // 0..8191
    const float* wg = Wg + (size_t)row * D;
    const float* wu = Wu + (size_t)row * D;
    float accg = 0.f, accu = 0.f;
    #pragma unroll 4
    for (int it = 0; it < D / 256; it++) {
        int c = it * 256 + lane * 4;
        float4 hv = *reinterpret_cast<const float4*>(hn + c);
        float4 gv = *reinterpret_cast<const float4*>(wg + c);
        float4 uv = *reinterpret_cast<const float4*>(wu + c);
        accg = fmaf(gv.x, hv.x, fmaf(gv.y, hv.y, fmaf(gv.z, hv.z, fmaf(gv.w, hv.w, accg))));
        accu = fmaf(uv.x, hv.x, fmaf(uv.y, hv.y, fmaf(uv.z, hv.z, fmaf(uv.w, hv.w, accu))));
    }
    accg = warp_sum(accg);
    accu = warp_sum(accu);
    if (lane == 0) act[row] = gelu_tanh(accg) * accu;
}

// ---------- pl gate GEMV: g[row] = gelu(W[row].x) * per_layer[row], rows=256 ----------
__global__ void gemv_plgate(const float* __restrict__ Wm, const float* __restrict__ x,
                            const float* __restrict__ per_layer, float* __restrict__ g) {
    int lane = threadIdx.x & 63, wid = threadIdx.x >> 6;
    int row = blockIdx.x * 4 + wid; // 0..255
    const float* wr = Wm + (size_t)row * D;
    float acc = 0.f;
    #pragma unroll 4
    for (int it = 0; it < D / 256; it++) {
        int c = it * 256 + lane * 4;
        float4 wv = *reinterpret_cast<const float4*>(wr + c);
        float4 xv = *reinterpret_cast<const float4*>(x + c);
        acc = fmaf(wv.x, xv.x, fmaf(wv.y, xv.y, fmaf(wv.z, xv.z, fmaf(wv.w, xv.w, acc))));
    }
    acc = warp_sum(acc);
    if (lane == 0) g[row] = gelu_tanh(acc) * per_layer[row];
}

// ---------- x1 = res + rmsnorm(y, w1); hn = rmsnorm(x1, w2). 1 block x 256 ----------
__global__ void post_attn_fused(const float* __restrict__ res, const float* __restrict__ y,
                                const float* __restrict__ w1, const float* __restrict__ w2,
                                float* __restrict__ x1, float* __restrict__ hn) {
    __shared__ float s4[4];
    int t = threadIdx.x;
    float yv[8], ss = 0.f;
    #pragma unroll
    for (int i = 0; i < 8; i++) { yv[i] = y[t + i * 256]; ss += yv[i] * yv[i]; }
    float tot = block_sum256(ss, s4);
    float rs = rsqrtf(tot / (float)D + EPS);
    float xv[8]; ss = 0.f;
    #pragma unroll
    for (int i = 0; i < 8; i++) {
        int idx = t + i * 256;
        float v = res[idx] + yv[i] * rs * (1.f + w1[idx]);
        xv[i] = v; x1[idx] = v; ss += v * v;
    }
    tot = block_sum256(ss, s4);
    rs = rsqrtf(tot / (float)D + EPS);
    #pragma unroll
    for (int i = 0; i < 8; i++) {
        int idx = t + i * 256;
        hn[idx] = xv[i] * rs * (1.f + w2[idx]);
    }
}

// ---------- x2 = res + rmsnorm(y, w). 1 block x 256 ----------
__global__ void residual_rms(const float* __restrict__ res, const float* __restrict__ y,
                             const float* __restrict__ w, float* __restrict__ out) {
    __shared__ float s4[4];
    int t = threadIdx.x;
    float yv[8], ss = 0.f;
    #pragma unroll
    for (int i = 0; i < 8; i++) { yv[i] = y[t + i * 256]; ss += yv[i] * yv[i]; }
    float tot = block_sum256(ss, s4);
    float rs = rsqrtf(tot / (float)D + EPS);
    #pragma unroll
    for (int i = 0; i < 8; i++) {
        int idx = t + i * 256;
        out[idx] = res[idx] + yv[i] * rs * (1.f + w[idx]);
    }
}

// ---------- out = (x2 + rmsnorm(g2, w)) * layer_scalar. 1 block x 256 ----------
__global__ void final_kernel(const float* __restrict__ x2, const float* __restrict__ g2,
                             const float* __restrict__ w, const float* __restrict__ scal,
                             float* __restrict__ out) {
    __shared__ float s4[4];
    int t = threadIdx.x;
    float gv[8], ss = 0.f;
    #pragma unroll
    for (int i = 0; i < 8; i++) { gv[i] = g2[t + i * 256]; ss += gv[i] * gv[i]; }
    float tot = block_sum256(ss, s4);
    float rs = rsqrtf(tot / (float)D + EPS);
    float sc = scal[0];
    #pragma unroll
    for (int i = 0; i < 8; i++) {
        int idx = t + i * 256;
        out[idx] = (x2[idx] + gv[i] * rs * (1.f + w[idx])) * sc;
    }
}

extern "C" void kernel_launch(void* const* d_in, const int* in_sizes, int n_in,
                              void* d_out, int out_size, void* d_ws, size_t ws_size,
                              hipStream_t stream) {
    const float* x_in        = (const float*)d_in[0];
    const float* cosv        = (const float*)d_in[1];
    const float* sinv        = (const float*)d_in[2];
    const float* mask        = (const float*)d_in[3];
    const float* kvc         = (const float*)d_in[4];
    const float* per_layer   = (const float*)d_in[5];
    const float* ln_in_w     = (const float*)d_in[6];
    const float* Wq          = (const float*)d_in[7];
    const float* q_norm_w    = (const float*)d_in[8];
    const float* Wk          = (const float*)d_in[9];
    const float* Wv          = (const float*)d_in[10];
    const float* k_norm_w    = (const float*)d_in[11];
    const float* Wo          = (const float*)d_in[12];
    const float* post_attn_w = (const float*)d_in[13];
    const float* pre_ffn_w   = (const float*)d_in[14];
    const float* Wgate       = (const float*)d_in[15];
    const float* Wup         = (const float*)d_in[16];
    const float* Wdown       = (const float*)d_in[17];
    const float* post_ffn_w  = (const float*)d_in[18];
    const float* Wpl_gate    = (const float*)d_in[19];
    const float* Wpl_proj    = (const float*)d_in[20];
    const float* post_pl_w   = (const float*)d_in[21];
    const float* layer_scal  = (const float*)d_in[22];
    const int*   ring_pos    = (const int*)d_in[23];
    float* out = (float*)d_out;
    float* ws  = (float*)d_ws;

    float* h      = ws;          // 2048
    float* qraw   = ws + 2048;   // 2048
    float* kraw   = ws + 4096;   // 512
    float* vraw   = ws + 4608;   // 512
    float* qf     = ws + 5120;   // 2048
    float* kf     = ws + 7168;   // 512
    float* vf     = ws + 7680;   // 512
    float* scores = ws + 8192;   // 8*512
    float* attn_o = ws + 12288;  // 2048
    float* y_wo   = ws + 14336;  // 2048
    float* x1     = ws + 16384;  // 2048
    float* hn     = ws + 18432;  // 2048
    float* act    = ws + 20480;  // 8192
    float* y2     = ws + 28672;  // 2048
    float* x2     = ws + 30720;  // 2048
    float* g      = ws + 32768;  // 256
    float* g2     = ws + 33024;  // 2048

    rms_in_kernel<<<1, 256, 0, stream>>>(x_in, ln_in_w, h);
    gemv_qkv<<<768, 256, 0, stream>>>(Wq, Wk, Wv, h, qraw, kraw, vraw);
    head_norm_rope<<<12, 256, 0, stream>>>(qraw, kraw, vraw, q_norm_w, k_norm_w,
                                           cosv, sinv, qf, kf, vf);
    attn_scores<<<64, 256, 0, stream>>>(kvc, kf, mask, qf, ring_pos, scores);
    attn_softmax<<<8, 256, 0, stream>>>(scores, attn_o);
    attn_o_partial<<<64, 256, 0, stream>>>(kvc, vf, scores, ring_pos, attn_o);
    gemv<2048><<<512, 256, 0, stream>>>(Wo, attn_o, y_wo);
    post_attn_fused<<<1, 256, 0, stream>>>(x_in, y_wo, post_attn_w, pre_ffn_w, x1, hn);
    gemv_gateup<<<2048, 256, 0, stream>>>(Wgate, Wup, hn, act);
    gemv<8192><<<512, 256, 0, stream>>>(Wdown, act, y2);
    residual_rms<<<1, 256, 0, stream>>>(x1, y2, post_ffn_w, x2);
    gemv_plgate<<<64, 256, 0, stream>>>(Wpl_gate, x2, per_layer, g);
    gemv<256><<<512, 256, 0, stream>>>(Wpl_proj, g, g2);
    final_kernel<<<1, 256, 0, stream>>>(x2, g2, post_pl_w, layer_scal, out);
}